// Round 3
// baseline (135.482 us; speedup 1.0000x reference)
//
#include <hip/hip_runtime.h>

// BlockSparseAttention B=2,H=16,N=2048,D=64 fp32, block-causal.
// R8 = R7 resubmitted byte-for-byte (3rd consecutive GPU acquisition timeout;
// no measurements of R6/R7 exist -> holding position, not stacking changes).
// R7 = R6 (2x q-rows per wave, grid 512, paired {i,15-i} schedule)
//    + T5 s_setprio(1) around the QK and PV MFMA clusters.
// Blob images identical to R3/R4/R5 (verified).

typedef short bf16x8 __attribute__((ext_vector_type(8)));
typedef float f32x4  __attribute__((ext_vector_type(4)));
typedef unsigned short u16;
typedef u16 u16x8 __attribute__((ext_vector_type(8)));

#define MFMA(A,B,C) __builtin_amdgcn_mfma_f32_16x16x32_bf16((A),(B),(C),0,0,0)

__device__ __forceinline__ u16 f2bf_rne(float f) {
    union { float f; unsigned u; } c; c.f = f;
    unsigned r = c.u + 0x7FFFu + ((c.u >> 16) & 1u);
    return (u16)(r >> 16);
}
__device__ __forceinline__ u16 f2bf_fast(float f) {
    union { float f; unsigned u; } c; c.f = f;
    return (u16)((c.u + 0x8000u) >> 16);
}

// async DMA: 16 B per lane, lands at wave-uniform lds base + lane*16
__device__ __forceinline__ void gload_lds16(const void* g, void* lds) {
    __builtin_amdgcn_global_load_lds(
        (const __attribute__((address_space(1))) unsigned int*)g,
        (__attribute__((address_space(3))) unsigned int*)lds, 16, 0, 0);
}

// ---- prepass (unchanged, verified): per (bh,64-key tile) 16KB blob ----
// K-image: u16 idx = key*64 + ((ch + (key&3) + 4*((key>>3)&1))&7)*8 + (d&7), ch=d>>3
// V-image: u16 idx = 4096 + d*64 + (((key>>3) + (d&7))&7)*8 + (key&7)
__global__ __launch_bounds__(256)
void prep_kernel(const float* __restrict__ K, const float* __restrict__ V,
                 u16* __restrict__ blob)
{
    int bt = blockIdx.x;
    int tid = threadIdx.x;
    const size_t gbase = (size_t)bt * 4096;
    u16* bb = blob + (size_t)bt * 8192;
    __shared__ __align__(16) u16 lt[4096];
    {
        int key = tid >> 2, c2 = (tid & 3) << 1;
        int rotb = (key & 3) + 4 * ((key >> 3) & 1);
        const float* kp = K + gbase + key * 64 + c2 * 8;
        float4 x0 = *(const float4*)kp,       x1 = *(const float4*)(kp + 4);
        float4 x2 = *(const float4*)(kp + 8), x3 = *(const float4*)(kp + 12);
        u16x8 a, b;
        a[0]=f2bf_rne(x0.x); a[1]=f2bf_rne(x0.y); a[2]=f2bf_rne(x0.z); a[3]=f2bf_rne(x0.w);
        a[4]=f2bf_rne(x1.x); a[5]=f2bf_rne(x1.y); a[6]=f2bf_rne(x1.z); a[7]=f2bf_rne(x1.w);
        b[0]=f2bf_rne(x2.x); b[1]=f2bf_rne(x2.y); b[2]=f2bf_rne(x2.z); b[3]=f2bf_rne(x2.w);
        b[4]=f2bf_rne(x3.x); b[5]=f2bf_rne(x3.y); b[6]=f2bf_rne(x3.z); b[7]=f2bf_rne(x3.w);
        *(u16x8*)&bb[key * 64 + (((c2    ) + rotb) & 7) * 8] = a;
        *(u16x8*)&bb[key * 64 + (((c2 + 1) + rotb) & 7) * 8] = b;
    }
    {
        int wv = tid >> 6, ln = tid & 63;
        const float* vp = V + gbase + ln * 64 + wv * 16;
        float4 y0 = *(const float4*)vp,       y1 = *(const float4*)(vp + 4);
        float4 y2 = *(const float4*)(vp + 8), y3 = *(const float4*)(vp + 12);
        float yy[16] = { y0.x,y0.y,y0.z,y0.w, y1.x,y1.y,y1.z,y1.w,
                         y2.x,y2.y,y2.z,y2.w, y3.x,y3.y,y3.z,y3.w };
        int kc = ln >> 3, kw = ln & 7;
        #pragma unroll
        for (int j = 0; j < 16; ++j) {
            int d = wv * 16 + j;
            lt[d * 64 + ((kc + (j & 7)) & 7) * 8 + kw] = f2bf_rne(yy[j]);
        }
    }
    __syncthreads();
    {
        int o = tid * 16;
        *(u16x8*)&bb[4096 + o]     = *(const u16x8*)&lt[o];
        *(u16x8*)&bb[4096 + o + 8] = *(const u16x8*)&lt[o + 8];
    }
}

// ---- main: 512 WGs, 128 q-rows each, 32 q-rows (2 frags) per wave ----
__global__ __launch_bounds__(256, 2)
void bsattn_main(const float* __restrict__ Q, const float* __restrict__ SC,
                 const int* __restrict__ RS, const int* __restrict__ RE,
                 const u16* __restrict__ blob, float* __restrict__ O)
{
    constexpr int N = 2048, D = 64;
    int wg = blockIdx.x;
    int bh = wg & 31;
    int i0 = wg >> 5;                     // [0,16)
    // wg and wg+256 land on the same CU; pair {i, 15-i} -> 36 tiles per CU.
    int qsub = (i0 < 8) ? i0 : 23 - i0;   // [0,16)
    int q0 = qsub << 7;                   // 128-row q tile

    int tid = threadIdx.x, wid = tid >> 6, lane = tid & 63;
    int n = lane & 15, g = lane >> 4;

    __shared__ __align__(16) u16 lsm[16384];   // 2 x 16KB tile buffers
    __shared__ int sbi[8];

    int row0 = q0 + wid * 32 + n;          // fragment A row
    int row1 = row0 + 16;                  // fragment B row
    int rs_l0 = RS[row0], re_l0 = RE[row0];
    int rs_l1 = RS[row1], re_l1 = RE[row1];
    int w_rs_min = min(rs_l0, rs_l1), w_rs_max = max(rs_l0, rs_l1);
    int w_re_min = min(re_l0, re_l1), w_re_max = max(re_l0, re_l1);
    #pragma unroll
    for (int o = 1; o < 16; o <<= 1) {
        w_rs_min = min(w_rs_min, __shfl_xor(w_rs_min, o));
        w_rs_max = max(w_rs_max, __shfl_xor(w_rs_max, o));
        w_re_min = min(w_re_min, __shfl_xor(w_re_min, o));
        w_re_max = max(w_re_max, __shfl_xor(w_re_max, o));
    }
    if (lane == 0) { sbi[wid * 2] = w_rs_min; sbi[wid * 2 + 1] = w_re_max; }

    float sscale = SC[0] * 1.44269504088896340736f;   // exp2 domain

    bf16x8 qA0, qA1, qB0, qB1;
    {
        const float* qp = Q + ((size_t)bh * N + row0) * D + g * 8;
        float4 a0 = *(const float4*)qp,        a1 = *(const float4*)(qp + 4);
        float4 b0 = *(const float4*)(qp + 32), b1 = *(const float4*)(qp + 36);
        qA0[0]=f2bf_rne(a0.x*sscale); qA0[1]=f2bf_rne(a0.y*sscale);
        qA0[2]=f2bf_rne(a0.z*sscale); qA0[3]=f2bf_rne(a0.w*sscale);
        qA0[4]=f2bf_rne(a1.x*sscale); qA0[5]=f2bf_rne(a1.y*sscale);
        qA0[6]=f2bf_rne(a1.z*sscale); qA0[7]=f2bf_rne(a1.w*sscale);
        qA1[0]=f2bf_rne(b0.x*sscale); qA1[1]=f2bf_rne(b0.y*sscale);
        qA1[2]=f2bf_rne(b0.z*sscale); qA1[3]=f2bf_rne(b0.w*sscale);
        qA1[4]=f2bf_rne(b1.x*sscale); qA1[5]=f2bf_rne(b1.y*sscale);
        qA1[6]=f2bf_rne(b1.z*sscale); qA1[7]=f2bf_rne(b1.w*sscale);
    }
    {
        const float* qp = Q + ((size_t)bh * N + row1) * D + g * 8;
        float4 a0 = *(const float4*)qp,        a1 = *(const float4*)(qp + 4);
        float4 b0 = *(const float4*)(qp + 32), b1 = *(const float4*)(qp + 36);
        qB0[0]=f2bf_rne(a0.x*sscale); qB0[1]=f2bf_rne(a0.y*sscale);
        qB0[2]=f2bf_rne(a0.z*sscale); qB0[3]=f2bf_rne(a0.w*sscale);
        qB0[4]=f2bf_rne(a1.x*sscale); qB0[5]=f2bf_rne(a1.y*sscale);
        qB0[6]=f2bf_rne(a1.z*sscale); qB0[7]=f2bf_rne(a1.w*sscale);
        qB1[0]=f2bf_rne(b0.x*sscale); qB1[1]=f2bf_rne(b0.y*sscale);
        qB1[2]=f2bf_rne(b0.z*sscale); qB1[3]=f2bf_rne(b0.w*sscale);
        qB1[4]=f2bf_rne(b1.x*sscale); qB1[5]=f2bf_rne(b1.y*sscale);
        qB1[6]=f2bf_rne(b1.z*sscale); qB1[7]=f2bf_rne(b1.w*sscale);
    }

    __syncthreads();
    int kst  = min(min(sbi[0], sbi[2]), min(sbi[4], sbi[6])) & ~63;
    int kend = max(max(sbi[1], sbi[3]), max(sbi[5], sbi[7]));
    int t0 = kst >> 6;
    int w  = (kend - kst + 63) >> 6;

    // loop-invariant LDS read offsets (u16 indices; verified images)
    int rA   = ((n >> 2) << 3) + (n & 3);
    int phk  = (n & 3) + 4 * ((n >> 2) & 1);
    int osA0 = rA * 64 + ((g + phk) & 7) * 8;
    int osA1 = rA * 64 + ((g + 4 + phk) & 7) * 8;
    int ov0  = 4096 + n * 64 + ((    g + (n & 7)) & 7) * 8;
    int ov1  = 4096 + n * 64 + ((4 + g + (n & 7)) & 7) * 8;

    f32x4 accA[4], accB[4];
    f32x4 acclA = {0.f,0.f,0.f,0.f}, acclB = {0.f,0.f,0.f,0.f};
    #pragma unroll
    for (int c = 0; c < 4; ++c) {
        accA[c] = (f32x4){0.f,0.f,0.f,0.f};
        accB[c] = (f32x4){0.f,0.f,0.f,0.f};
    }
    bf16x8 ones;
    #pragma unroll
    for (int j = 0; j < 8; ++j) ones[j] = (short)0x3F80;

    auto stage = [&](int i) {               // async DMA of tile t0+i into buf[i&1]
        if (i < w) {
            const u16* src = blob + (size_t)(bh * 32 + t0 + i) * 8192;
            u16* dst = &lsm[(i & 1) << 13];
            int wb = wid * 2048;             // wave-uniform
            #pragma unroll
            for (int c = 0; c < 4; ++c)
                gload_lds16(src + wb + c * 512 + lane * 8, dst + wb + c * 512);
        }
    };

    auto proc = [&](int kb, const u16* ls) {
        bool bdry = (kb < w_rs_max) || (kb + 64 > w_re_min);   // wave-uniform
        #pragma unroll
        for (int h = 0; h < 2; ++h) {
            int hb = h * 2048;
            // K fragments: read once, used by BOTH q-fragments
            bf16x8 k00 = *(const bf16x8*)&ls[hb + osA0];
            bf16x8 k01 = *(const bf16x8*)&ls[hb + osA1];
            bf16x8 k10 = *(const bf16x8*)&ls[hb + osA0 + 256];
            bf16x8 k11 = *(const bf16x8*)&ls[hb + osA1 + 256];
            f32x4 tA0 = {0.f,0.f,0.f,0.f}, tA1 = tA0, tB0 = tA0, tB1 = tA0;
            __builtin_amdgcn_s_setprio(1);
            tA0 = MFMA(k00, qA0, tA0); tA0 = MFMA(k01, qA1, tA0);
            tA1 = MFMA(k10, qA0, tA1); tA1 = MFMA(k11, qA1, tA1);
            tB0 = MFMA(k00, qB0, tB0); tB0 = MFMA(k01, qB1, tB0);
            tB1 = MFMA(k10, qB0, tB1); tB1 = MFMA(k11, qB1, tB1);
            __builtin_amdgcn_s_setprio(0);
            float sA[8], sB[8];
            #pragma unroll
            for (int r = 0; r < 4; ++r) {
                sA[r] = tA0[r]; sA[4 + r] = tA1[r];
                sB[r] = tB0[r]; sB[4 + r] = tB1[r];
            }
            if (bdry) {                      // boundary tiles only
                #pragma unroll
                for (int j = 0; j < 8; ++j) {
                    int key = kb + h * 32 + g * 8 + j;
                    if (key < rs_l0 || key >= re_l0) sA[j] = -1e30f;
                    if (key < rs_l1 || key >= re_l1) sB[j] = -1e30f;
                }
            }
            bf16x8 pA, pB;
            #pragma unroll
            for (int j = 0; j < 8; ++j) { float p = __builtin_amdgcn_exp2f(sA[j]); pA[j] = (short)f2bf_fast(p); }
            #pragma unroll
            for (int j = 0; j < 8; ++j) { float p = __builtin_amdgcn_exp2f(sB[j]); pB[j] = (short)f2bf_fast(p); }
            // V fragments: read once, used by BOTH q-fragments
            int ov = h ? ov1 : ov0;
            bf16x8 v0 = *(const bf16x8*)&ls[ov       ];
            bf16x8 v1 = *(const bf16x8*)&ls[ov + 1024];
            bf16x8 v2 = *(const bf16x8*)&ls[ov + 2048];
            bf16x8 v3 = *(const bf16x8*)&ls[ov + 3072];
            __builtin_amdgcn_s_setprio(1);
            accA[0] = MFMA(pA, v0, accA[0]);
            accA[1] = MFMA(pA, v1, accA[1]);
            accA[2] = MFMA(pA, v2, accA[2]);
            accA[3] = MFMA(pA, v3, accA[3]);
            acclA   = MFMA(pA, ones, acclA);
            accB[0] = MFMA(pB, v0, accB[0]);
            accB[1] = MFMA(pB, v1, accB[1]);
            accB[2] = MFMA(pB, v2, accB[2]);
            accB[3] = MFMA(pB, v3, accB[3]);
            acclB   = MFMA(pB, ones, acclB);
            __builtin_amdgcn_s_setprio(0);
        }
    };

    stage(0);
    for (int i = 0; i < w; ++i) {
        __syncthreads();          // drains vmcnt: buf[i&1] ready; buf[(i+1)&1] free
        stage(i + 1);             // prefetch overlaps proc below
        proc(kst + (i << 6), &lsm[(i & 1) << 13]);
    }

    // epilogue: frag A rows q0+wid*32+4g+r, frag B rows +16; cols 16c+n
    int rb = g << 2;
    {
        int orow = q0 + wid * 32 + rb;
        float* ob = O + ((size_t)bh * N + orow) * D + n;
        #pragma unroll
        for (int r = 0; r < 4; ++r) {
            float li = 1.0f / acclA[r];
            float* rp = ob + (size_t)r * D;
            rp[0]  = accA[0][r] * li;
            rp[16] = accA[1][r] * li;
            rp[32] = accA[2][r] * li;
            rp[48] = accA[3][r] * li;
        }
    }
    {
        int orow = q0 + wid * 32 + 16 + rb;
        float* ob = O + ((size_t)bh * N + orow) * D + n;
        #pragma unroll
        for (int r = 0; r < 4; ++r) {
            float li = 1.0f / acclB[r];
            float* rp = ob + (size_t)r * D;
            rp[0]  = accB[0][r] * li;
            rp[16] = accB[1][r] * li;
            rp[32] = accB[2][r] * li;
            rp[48] = accB[3][r] * li;
        }
    }
}

extern "C" void kernel_launch(void* const* d_in, const int* in_sizes, int n_in,
                              void* d_out, int out_size, void* d_ws, size_t ws_size,
                              hipStream_t stream) {
    const float* q  = (const float*)d_in[0];
    const float* k  = (const float*)d_in[1];
    const float* v  = (const float*)d_in[2];
    const float* sc = (const float*)d_in[3];
    const int* rs   = (const int*)d_in[4];
    const int* re   = (const int*)d_in[5];
    float* out      = (float*)d_out;
    u16* blob       = (u16*)d_ws;   // 32 bh * 32 tiles * 16KB = 16.8 MB

    prep_kernel<<<dim3(1024), dim3(256), 0, stream>>>(k, v, blob);
    bsattn_main<<<dim3(512), dim3(256), 0, stream>>>(q, sc, rs, re, blob, out);
}

// Round 7
// 130.777 us; speedup vs baseline: 1.0360x; 1.0360x over previous
//
#include <hip/hip_runtime.h>

// BlockSparseAttention B=2,H=16,N=2048,D=64 fp32, block-causal.
// R12 = R9 single-kernel fusion + load-hoist (deeper staging pipeline).
// Loop: {barrier; proc(i); stage_write(i+1); stage_load(i+2)} — each f32 tile
// load is in flight across write+barrier+proc (~2x cover) before its consumer.
// Numerics BIT-IDENTICAL to R7 (verified, main=45.5us) and R9: same LDS images,
//   K-image: u16 idx = key*64 + ((ch + (key&3) + 4*((key>>3)&1))&7)*8 + (d&7)
//   V-image: u16 idx = 4096 + d*64 + (((key>>3) + (d&7))&7)*8 + (key&7)
// R7 counters: main 45.5us, ~68% stall cycles (staging latency + barrier drain;
// blob was L3-resident => latency-bound not BW-bound); total 135.5us of which
// ~90us was prep kernel + inter-dispatch gap -> deleted by fusion.

typedef short bf16x8 __attribute__((ext_vector_type(8)));
typedef float f32x4  __attribute__((ext_vector_type(4)));
typedef unsigned short u16;
typedef u16 u16x8 __attribute__((ext_vector_type(8)));

#define MFMA(A,B,C) __builtin_amdgcn_mfma_f32_16x16x32_bf16((A),(B),(C),0,0,0)

__device__ __forceinline__ u16 f2bf_rne(float f) {
    union { float f; unsigned u; } c; c.f = f;
    unsigned r = c.u + 0x7FFFu + ((c.u >> 16) & 1u);
    return (u16)(r >> 16);
}
__device__ __forceinline__ u16 f2bf_fast(float f) {
    union { float f; unsigned u; } c; c.f = f;
    return (u16)((c.u + 0x8000u) >> 16);
}

// ---- main (fused): 512 WGs, 128 q-rows each, 32 q-rows (2 frags) per wave ----
__global__ __launch_bounds__(256, 2)
void bsattn_fused(const float* __restrict__ Q, const float* __restrict__ K,
                  const float* __restrict__ V, const float* __restrict__ SC,
                  const int* __restrict__ RS, const int* __restrict__ RE,
                  float* __restrict__ O)
{
    constexpr int N = 2048, D = 64;
    int wg = blockIdx.x;
    int bh = wg & 31;
    int i0 = wg >> 5;                     // [0,16)
    // wg and wg+256 land on the same CU; pair {i, 15-i} -> 36 tiles per CU.
    int qsub = (i0 < 8) ? i0 : 23 - i0;   // [0,16)
    int q0 = qsub << 7;                   // 128-row q tile

    int tid = threadIdx.x, wid = tid >> 6, lane = tid & 63;
    int n = lane & 15, g = lane >> 4;

    __shared__ __align__(16) u16 lsm[16384];   // 2 x 16KB tile buffers
    __shared__ int sbi[8];

    int row0 = q0 + wid * 32 + n;          // fragment A row
    int row1 = row0 + 16;                  // fragment B row
    int rs_l0 = RS[row0], re_l0 = RE[row0];
    int rs_l1 = RS[row1], re_l1 = RE[row1];
    int w_rs_min = min(rs_l0, rs_l1), w_rs_max = max(rs_l0, rs_l1);
    int w_re_min = min(re_l0, re_l1), w_re_max = max(re_l0, re_l1);
    #pragma unroll
    for (int o = 1; o < 16; o <<= 1) {
        w_rs_min = min(w_rs_min, __shfl_xor(w_rs_min, o));
        w_rs_max = max(w_rs_max, __shfl_xor(w_rs_max, o));
        w_re_min = min(w_re_min, __shfl_xor(w_re_min, o));
        w_re_max = max(w_re_max, __shfl_xor(w_re_max, o));
    }
    if (lane == 0) { sbi[wid * 2] = w_rs_min; sbi[wid * 2 + 1] = w_re_max; }

    float sscale = SC[0] * 1.44269504088896340736f;   // exp2 domain

    bf16x8 qA0, qA1, qB0, qB1;
    {
        const float* qp = Q + ((size_t)bh * N + row0) * D + g * 8;
        float4 a0 = *(const float4*)qp,        a1 = *(const float4*)(qp + 4);
        float4 b0 = *(const float4*)(qp + 32), b1 = *(const float4*)(qp + 36);
        qA0[0]=f2bf_rne(a0.x*sscale); qA0[1]=f2bf_rne(a0.y*sscale);
        qA0[2]=f2bf_rne(a0.z*sscale); qA0[3]=f2bf_rne(a0.w*sscale);
        qA0[4]=f2bf_rne(a1.x*sscale); qA0[5]=f2bf_rne(a1.y*sscale);
        qA0[6]=f2bf_rne(a1.z*sscale); qA0[7]=f2bf_rne(a1.w*sscale);
        qA1[0]=f2bf_rne(b0.x*sscale); qA1[1]=f2bf_rne(b0.y*sscale);
        qA1[2]=f2bf_rne(b0.z*sscale); qA1[3]=f2bf_rne(b0.w*sscale);
        qA1[4]=f2bf_rne(b1.x*sscale); qA1[5]=f2bf_rne(b1.y*sscale);
        qA1[6]=f2bf_rne(b1.z*sscale); qA1[7]=f2bf_rne(b1.w*sscale);
    }
    {
        const float* qp = Q + ((size_t)bh * N + row1) * D + g * 8;
        float4 a0 = *(const float4*)qp,        a1 = *(const float4*)(qp + 4);
        float4 b0 = *(const float4*)(qp + 32), b1 = *(const float4*)(qp + 36);
        qB0[0]=f2bf_rne(a0.x*sscale); qB0[1]=f2bf_rne(a0.y*sscale);
        qB0[2]=f2bf_rne(a0.z*sscale); qB0[3]=f2bf_rne(a0.w*sscale);
        qB0[4]=f2bf_rne(a1.x*sscale); qB0[5]=f2bf_rne(a1.y*sscale);
        qB0[6]=f2bf_rne(a1.z*sscale); qB0[7]=f2bf_rne(a1.w*sscale);
        qB1[0]=f2bf_rne(b0.x*sscale); qB1[1]=f2bf_rne(b0.y*sscale);
        qB1[2]=f2bf_rne(b0.z*sscale); qB1[3]=f2bf_rne(b0.w*sscale);
        qB1[4]=f2bf_rne(b1.x*sscale); qB1[5]=f2bf_rne(b1.y*sscale);
        qB1[6]=f2bf_rne(b1.z*sscale); qB1[7]=f2bf_rne(b1.w*sscale);
    }

    __syncthreads();
    int kst  = min(min(sbi[0], sbi[2]), min(sbi[4], sbi[6])) & ~63;
    int kend = max(max(sbi[1], sbi[3]), max(sbi[5], sbi[7]));
    int t0 = kst >> 6;
    int w  = (kend - kst + 63) >> 6;

    // loop-invariant LDS read offsets (u16 indices; verified images)
    int rA   = ((n >> 2) << 3) + (n & 3);
    int phk  = (n & 3) + 4 * ((n >> 2) & 1);
    int osA0 = rA * 64 + ((g + phk) & 7) * 8;
    int osA1 = rA * 64 + ((g + 4 + phk) & 7) * 8;
    int ov0  = 4096 + n * 64 + ((    g + (n & 7)) & 7) * 8;
    int ov1  = 4096 + n * 64 + ((4 + g + (n & 7)) & 7) * 8;

    // loop-invariant STAGING coords (formulas identical to the verified prep kernel)
    int key_l = tid >> 2, c2 = (tid & 3) << 1;                 // K: thread -> (key, dim-chunk)
    int rotb  = (key_l & 3) + 4 * ((key_l >> 3) & 1);
    int kiA   = key_l * 64 + (((c2    ) + rotb) & 7) * 8;      // K-image write offsets
    int kiB   = key_l * 64 + (((c2 + 1) + rotb) & 7) * 8;
    int kc    = lane >> 3, kw = lane & 7;                      // V: thread -> (key=lane, dims wid*16..)
    const float* Kb = K + (size_t)bh * N * D;
    const float* Vb = V + (size_t)bh * N * D;

    f32x4 accA[4], accB[4];
    f32x4 acclA = {0.f,0.f,0.f,0.f}, acclB = {0.f,0.f,0.f,0.f};
    #pragma unroll
    for (int c = 0; c < 4; ++c) {
        accA[c] = (f32x4){0.f,0.f,0.f,0.f};
        accB[c] = (f32x4){0.f,0.f,0.f,0.f};
    }
    bf16x8 ones;
    #pragma unroll
    for (int j = 0; j < 8; ++j) ones[j] = (short)0x3F80;

    // in-flight f32 tile staged in registers (issue ~2 tiles early, write late)
    float4 kf0, kf1, kf2, kf3, vf0, vf1, vf2, vf3;

    auto stage_load = [&](int i) {          // issue f32 global loads for tile t0+i
        if (i < w) {
            const float* kp = Kb + (size_t)(t0 + i) * 4096 + key_l * 64 + c2 * 8;
            kf0 = *(const float4*)kp;       kf1 = *(const float4*)(kp + 4);
            kf2 = *(const float4*)(kp + 8); kf3 = *(const float4*)(kp + 12);
            const float* vp = Vb + (size_t)(t0 + i) * 4096 + lane * 64 + wid * 16;
            vf0 = *(const float4*)vp;       vf1 = *(const float4*)(vp + 4);
            vf2 = *(const float4*)(vp + 8); vf3 = *(const float4*)(vp + 12);
        }
    };
    auto stage_write = [&](int i) {         // cvt + swizzled LDS image write
        if (i < w) {
            u16* dst = &lsm[(i & 1) << 13];
            u16x8 a, b;
            a[0]=f2bf_rne(kf0.x); a[1]=f2bf_rne(kf0.y); a[2]=f2bf_rne(kf0.z); a[3]=f2bf_rne(kf0.w);
            a[4]=f2bf_rne(kf1.x); a[5]=f2bf_rne(kf1.y); a[6]=f2bf_rne(kf1.z); a[7]=f2bf_rne(kf1.w);
            b[0]=f2bf_rne(kf2.x); b[1]=f2bf_rne(kf2.y); b[2]=f2bf_rne(kf2.z); b[3]=f2bf_rne(kf2.w);
            b[4]=f2bf_rne(kf3.x); b[5]=f2bf_rne(kf3.y); b[6]=f2bf_rne(kf3.z); b[7]=f2bf_rne(kf3.w);
            *(u16x8*)&dst[kiA] = a;
            *(u16x8*)&dst[kiB] = b;
            float vy[16] = { vf0.x,vf0.y,vf0.z,vf0.w, vf1.x,vf1.y,vf1.z,vf1.w,
                             vf2.x,vf2.y,vf2.z,vf2.w, vf3.x,vf3.y,vf3.z,vf3.w };
            #pragma unroll
            for (int j = 0; j < 16; ++j) {
                int d = wid * 16 + j;
                dst[4096 + d * 64 + ((kc + (j & 7)) & 7) * 8 + kw] = f2bf_rne(vy[j]);
            }
        }
    };

    auto proc = [&](int kb, const u16* ls) {
        bool bdry = (kb < w_rs_max) || (kb + 64 > w_re_min);   // wave-uniform
        #pragma unroll
        for (int h = 0; h < 2; ++h) {
            int hb = h * 2048;
            // K fragments: read once, used by BOTH q-fragments
            bf16x8 k00 = *(const bf16x8*)&ls[hb + osA0];
            bf16x8 k01 = *(const bf16x8*)&ls[hb + osA1];
            bf16x8 k10 = *(const bf16x8*)&ls[hb + osA0 + 256];
            bf16x8 k11 = *(const bf16x8*)&ls[hb + osA1 + 256];
            f32x4 tA0 = {0.f,0.f,0.f,0.f}, tA1 = tA0, tB0 = tA0, tB1 = tA0;
            __builtin_amdgcn_s_setprio(1);
            tA0 = MFMA(k00, qA0, tA0); tA0 = MFMA(k01, qA1, tA0);
            tA1 = MFMA(k10, qA0, tA1); tA1 = MFMA(k11, qA1, tA1);
            tB0 = MFMA(k00, qB0, tB0); tB0 = MFMA(k01, qB1, tB0);
            tB1 = MFMA(k10, qB0, tB1); tB1 = MFMA(k11, qB1, tB1);
            __builtin_amdgcn_s_setprio(0);
            float sA[8], sB[8];
            #pragma unroll
            for (int r = 0; r < 4; ++r) {
                sA[r] = tA0[r]; sA[4 + r] = tA1[r];
                sB[r] = tB0[r]; sB[4 + r] = tB1[r];
            }
            if (bdry) {                      // boundary tiles only
                #pragma unroll
                for (int j = 0; j < 8; ++j) {
                    int key = kb + h * 32 + g * 8 + j;
                    if (key < rs_l0 || key >= re_l0) sA[j] = -1e30f;
                    if (key < rs_l1 || key >= re_l1) sB[j] = -1e30f;
                }
            }
            bf16x8 pA, pB;
            #pragma unroll
            for (int j = 0; j < 8; ++j) { float p = __builtin_amdgcn_exp2f(sA[j]); pA[j] = (short)f2bf_fast(p); }
            #pragma unroll
            for (int j = 0; j < 8; ++j) { float p = __builtin_amdgcn_exp2f(sB[j]); pB[j] = (short)f2bf_fast(p); }
            // V fragments: read once, used by BOTH q-fragments
            int ov = h ? ov1 : ov0;
            bf16x8 v0 = *(const bf16x8*)&ls[ov       ];
            bf16x8 v1 = *(const bf16x8*)&ls[ov + 1024];
            bf16x8 v2 = *(const bf16x8*)&ls[ov + 2048];
            bf16x8 v3 = *(const bf16x8*)&ls[ov + 3072];
            __builtin_amdgcn_s_setprio(1);
            accA[0] = MFMA(pA, v0, accA[0]);
            accA[1] = MFMA(pA, v1, accA[1]);
            accA[2] = MFMA(pA, v2, accA[2]);
            accA[3] = MFMA(pA, v3, accA[3]);
            acclA   = MFMA(pA, ones, acclA);
            accB[0] = MFMA(pB, v0, accB[0]);
            accB[1] = MFMA(pB, v1, accB[1]);
            accB[2] = MFMA(pB, v2, accB[2]);
            accB[3] = MFMA(pB, v3, accB[3]);
            acclB   = MFMA(pB, ones, acclB);
            __builtin_amdgcn_s_setprio(0);
        }
    };

    // prologue: tile 0 staged serially; tile 1's loads issued before the loop
    stage_load(0);
    stage_write(0);
    stage_load(1);
    for (int i = 0; i < w; ++i) {
        __syncthreads();          // buf[i&1] image complete; buf[(i+1)&1] free
        proc(kst + (i << 6), &lsm[(i & 1) << 13]);
        stage_write(i + 1);       // consumes loads issued one iteration ago
        stage_load(i + 2);        // in flight across barrier + proc(i+1)
    }

    // epilogue: frag A rows q0+wid*32+4g+r, frag B rows +16; cols 16c+n
    int rb = g << 2;
    {
        int orow = q0 + wid * 32 + rb;
        float* ob = O + ((size_t)bh * N + orow) * D + n;
        #pragma unroll
        for (int r = 0; r < 4; ++r) {
            float li = 1.0f / acclA[r];
            float* rp = ob + (size_t)r * D;
            rp[0]  = accA[0][r] * li;
            rp[16] = accA[1][r] * li;
            rp[32] = accA[2][r] * li;
            rp[48] = accA[3][r] * li;
        }
    }
    {
        int orow = q0 + wid * 32 + 16 + rb;
        float* ob = O + ((size_t)bh * N + orow) * D + n;
        #pragma unroll
        for (int r = 0; r < 4; ++r) {
            float li = 1.0f / acclB[r];
            float* rp = ob + (size_t)r * D;
            rp[0]  = accB[0][r] * li;
            rp[16] = accB[1][r] * li;
            rp[32] = accB[2][r] * li;
            rp[48] = accB[3][r] * li;
        }
    }
}

extern "C" void kernel_launch(void* const* d_in, const int* in_sizes, int n_in,
                              void* d_out, int out_size, void* d_ws, size_t ws_size,
                              hipStream_t stream) {
    const float* q  = (const float*)d_in[0];
    const float* k  = (const float*)d_in[1];
    const float* v  = (const float*)d_in[2];
    const float* sc = (const float*)d_in[3];
    const int* rs   = (const int*)d_in[4];
    const int* re   = (const int*)d_in[5];
    float* out      = (float*)d_out;

    bsattn_fused<<<dim3(512), dim3(256), 0, stream>>>(q, k, v, sc, rs, re, out);
}